// Round 5
// baseline (288.074 us; speedup 1.0000x reference)
//
#include <hip/hip_runtime.h>

// MultiBoxLoss, non-cooperative 4-kernel pipeline. IoU matrix computed ONCE.
// B=128 images, P=24564 priors, O=20 truths, 2 classes.
//
//   init_ws : zero per-truth packed-argmax array + accumulators
//   match   : per (b,p): 20 IoUs -> u8 state (thr bit | best-truth idx) in ws;
//             per-truth (iou,k) max -> packed key (iou_bits<<32 | ~p) atomicMax
//   fixup   : per image: each truth's best prior gets state = 0x80|o
//             (duplicates resolved to largest o == last-wins, as validated in R1)
//   loss    : per (b,p): state byte -> conf; smooth-L1 (positives) + focal (all);
//             block reduce -> atomicAdd
//   finalize: out[0]=loss_l/num_pos, out[1]=loss_c/num_pos
//
// Fallback (ws too small): R1-proven two-kernel path (IoU computed twice).

#define NB 128
#define NP 24564
#define NO 20

#define IPT1 12
#define NCH1 8            // 8*256*12 = 24576 >= 24564 (every thread has k=0 valid)
#define IPT2 4
#define NCH2 24           // 24*256*4 = 24576

// fast-path ws layout (bytes)
#define ST_BYTES  ((size_t)NB * NP)                 // 3,144,192 (8-aligned)
#define PK_OFF    ST_BYTES
#define ACC_OFF   (PK_OFF + (size_t)NB * NO * 8)
#define NPOS_OFF  (ACC_OFF + 16)
#define WS_NEEDED (NPOS_OFF + 8)

__global__ __launch_bounds__(256) void init_ws_kernel(unsigned long long* __restrict__ packed,
                                                      double* __restrict__ acc,
                                                      unsigned int* __restrict__ npos) {
    int i = blockIdx.x * 256 + threadIdx.x;
    if (i < NB * NO) packed[i] = 0ull;
    if (i == 0) { acc[0] = 0.0; acc[1] = 0.0; *npos = 0u; }
}

// ---------------------------------------------------------------- fast path
__global__ __launch_bounds__(256) void match_kernel(const float4* __restrict__ priors,
                                                    const float* __restrict__ bbox,
                                                    unsigned char* __restrict__ state,
                                                    unsigned long long* __restrict__ packed) {
    const int img  = blockIdx.x / NCH1;
    const int base = (blockIdx.x % NCH1) * (256 * IPT1);
    const int tid  = threadIdx.x;

    __shared__ float4 s_truth[NO];
    __shared__ float  s_area[NO];
    if (tid < NO) {
        const float* t = bbox + ((size_t)img * NO + tid) * 5;
        float4 tb = make_float4(t[0], t[1], t[2], t[3]);
        s_truth[tid] = tb;
        s_area[tid]  = (tb.z - tb.x) * (tb.w - tb.y);
    }
    __syncthreads();

    // per-truth running max as (f32 iou, iteration k): no 64-bit ops in the hot loop.
    // strict > keeps smallest k on ties -> smallest p within a thread (first occurrence).
    float bf[NO];
    int   bk[NO];
#pragma unroll
    for (int o = 0; o < NO; ++o) { bf[o] = -1.0f; bk[o] = 0; }

    for (int k = 0; k < IPT1; ++k) {
        const int p = base + k * 256 + tid;
        if (p >= NP) break;                   // only the tail chunk, monotone in k

        float4 pr = priors[p];                // center-form cx,cy,w,h
        float px0 = pr.x - pr.z * 0.5f, py0 = pr.y - pr.w * 0.5f;
        float px1 = pr.x + pr.z * 0.5f, py1 = pr.y + pr.w * 0.5f;
        float parea = (px1 - px0) * (py1 - py0);

        float bestv = -1.0f;
        int bi = 0;
#pragma unroll
        for (int o = 0; o < NO; ++o) {
            float4 tb = s_truth[o];
            float lx = fmaxf(tb.x, px0), ly = fmaxf(tb.y, py0);
            float rx = fminf(tb.z, px1), ry = fminf(tb.w, py1);
            float w = fmaxf(rx - lx, 0.0f);
            float h = fmaxf(ry - ly, 0.0f);
            float inter = w * h;
            float iou = inter / (s_area[o] + parea - inter);   // exact f32 semantics
            if (iou > bf[o]) { bf[o] = iou; bk[o] = k; }       // per-truth max
            if (iou > bestv) { bestv = iou; bi = o; }          // per-prior argmax (first occ.)
        }
        state[(size_t)img * NP + p] =
            (unsigned char)(bi | (bestv >= 0.5f ? 0x80 : 0));
    }

    // pack keys once per thread, butterfly-reduce per wave, one atomicMax per wave.
#pragma unroll
    for (int o = 0; o < NO; ++o) {
        const int p = base + bk[o] * 256 + tid;   // every thread executed k=0 -> bf[o]>=0
        unsigned long long v = ((unsigned long long)__float_as_uint(bf[o]) << 32)
                             | (unsigned long long)(0xFFFFFFFFu - (unsigned)p);
#pragma unroll
        for (int s = 32; s > 0; s >>= 1) {
            unsigned long long u = __shfl_xor(v, s, 64);
            v = (v > u) ? v : u;
        }
        if ((tid & 63) == 0) atomicMax(&packed[img * NO + o], v);
    }
}

__global__ __launch_bounds__(64) void fixup_kernel(const unsigned long long* __restrict__ packed,
                                                   unsigned char* __restrict__ state) {
    const int img = blockIdx.x;
    const int o   = threadIdx.x;
    int bp = -1;
    if (o < NO) {
        unsigned long long v = packed[(size_t)img * NO + o];
        bp = (int)(0xFFFFFFFFu - (unsigned)(v & 0xFFFFFFFFull));
    }
    // last-wins on duplicate best priors: only the largest o with this bp writes
    bool write = (o < NO);
#pragma unroll
    for (int o2 = 0; o2 < NO; ++o2) {
        int bp2 = __shfl(bp, o2, 64);
        if (o2 > o && bp2 == bp) write = false;
    }
    if (write) state[(size_t)img * NP + bp] = (unsigned char)(0x80 | o);
}

__global__ __launch_bounds__(256) void loss_kernel(const float4* __restrict__ loc_data,
                                                   const float2* __restrict__ conf_data,
                                                   const float4* __restrict__ priors,
                                                   const float* __restrict__ bbox,
                                                   const unsigned char* __restrict__ state,
                                                   double* __restrict__ acc,
                                                   unsigned int* __restrict__ npos) {
    const int img  = blockIdx.x / NCH2;
    const int base = (blockIdx.x % NCH2) * (256 * IPT2);
    const int tid  = threadIdx.x;

    __shared__ float4 s_truth[NO];
    __shared__ int    s_label[NO];
    if (tid < NO) {
        const float* t = bbox + ((size_t)img * NO + tid) * 5;
        s_truth[tid] = make_float4(t[0], t[1], t[2], t[3]);
        s_label[tid] = (int)t[4];
    }
    __syncthreads();

    float lossl = 0.0f, lossc = 0.0f;
    int np = 0;

    for (int k = 0; k < IPT2; ++k) {
        const int p = base + k * 256 + tid;
        if (p >= NP) break;

        const int st  = state[(size_t)img * NP + p];
        const int bi  = st & 0x1F;
        const bool thr = (st & 0x80) != 0;
        const int conf = thr ? (s_label[bi] + 1) : 0;

        if (conf > 0) {
            np++;
            float4 pr = priors[p];
            float4 m  = s_truth[bi];
            float gx = ((m.x + m.z) * 0.5f - pr.x) / (0.1f * pr.z);
            float gy = ((m.y + m.w) * 0.5f - pr.y) / (0.1f * pr.w);
            float gw = logf((m.z - m.x) / pr.z) / 0.2f;
            float gh = logf((m.w - m.y) / pr.w) / 0.2f;
            float4 ld = loc_data[(size_t)img * NP + p];
            float d0 = ld.x - gx, d1 = ld.y - gy, d2 = ld.z - gw, d3 = ld.w - gh;
            float a0 = fabsf(d0), a1 = fabsf(d1), a2 = fabsf(d2), a3 = fabsf(d3);
            lossl += (a0 < 1.0f) ? 0.5f * d0 * d0 : a0 - 0.5f;
            lossl += (a1 < 1.0f) ? 0.5f * d1 * d1 : a1 - 0.5f;
            lossl += (a2 < 1.0f) ? 0.5f * d2 * d2 : a2 - 0.5f;
            lossl += (a3 < 1.0f) ? 0.5f * d3 * d3 : a3 - 0.5f;
        }

        float2 cd = conf_data[(size_t)img * NP + p];
        float mx = fmaxf(cd.x, cd.y);
        float e0 = expf(cd.x - mx), e1 = expf(cd.y - mx);
        float sum = e0 + e1;
        if (conf <= 1) {
            float pc = ((conf == 0) ? e0 : e1) / sum;
            pc = fminf(fmaxf(pc, 1e-7f), 1.0f - 1e-7f);
            float om = 1.0f - pc;
            lossc += 0.25f * (-logf(pc)) * om * om;
        }
    }

#pragma unroll
    for (int s = 32; s > 0; s >>= 1) {
        lossl += __shfl_xor(lossl, s, 64);
        lossc += __shfl_xor(lossc, s, 64);
        np    += __shfl_xor(np, s, 64);
    }
    __shared__ float s_ll[4], s_lc[4];
    __shared__ int s_np[4];
    int wid = tid >> 6;
    if ((tid & 63) == 0) { s_ll[wid] = lossl; s_lc[wid] = lossc; s_np[wid] = np; }
    __syncthreads();
    if (tid == 0) {
        float tl = 0.0f, tc = 0.0f;
        int tn = 0;
        for (int w = 0; w < 4; ++w) { tl += s_ll[w]; tc += s_lc[w]; tn += s_np[w]; }
        atomicAdd(&acc[0], (double)tl);
        atomicAdd(&acc[1], (double)tc);
        atomicAdd(npos, (unsigned int)tn);
    }
}

__global__ __launch_bounds__(64) void finalize_kernel(const double* __restrict__ acc,
                                                      const unsigned int* __restrict__ npos,
                                                      float* __restrict__ out) {
    if (threadIdx.x == 0 && blockIdx.x == 0) {
        double np = (double)(*npos);
        if (np < 1.0) np = 1.0;
        out[0] = (float)(acc[0] / np);
        out[1] = (float)(acc[1] / np);
    }
}

// ------------------------------------------------- fallback path (R1-proven)
__global__ __launch_bounds__(256) void fb_best_prior_kernel(const float4* __restrict__ priors,
                                                            const float* __restrict__ bbox,
                                                            unsigned long long* __restrict__ packed) {
    const int b = blockIdx.x / NCH1;
    const int base = (blockIdx.x % NCH1) * (256 * IPT1);

    __shared__ float4 s_truth[NO];
    __shared__ float s_area[NO];
    if (threadIdx.x < NO) {
        const float* t = bbox + ((size_t)b * NO + threadIdx.x) * 5;
        float4 tb = make_float4(t[0], t[1], t[2], t[3]);
        s_truth[threadIdx.x] = tb;
        s_area[threadIdx.x] = (tb.z - tb.x) * (tb.w - tb.y);
    }
    __syncthreads();

    unsigned long long best[NO];
#pragma unroll
    for (int o = 0; o < NO; ++o) best[o] = 0ull;

    for (int k = 0; k < IPT1; ++k) {
        const int p = base + k * 256 + threadIdx.x;
        if (p < NP) {
            float4 pr = priors[p];
            float px0 = pr.x - pr.z * 0.5f, py0 = pr.y - pr.w * 0.5f;
            float px1 = pr.x + pr.z * 0.5f, py1 = pr.y + pr.w * 0.5f;
            float parea = (px1 - px0) * (py1 - py0);
            unsigned long long pkey = (unsigned long long)(0xFFFFFFFFu - (unsigned)p);
#pragma unroll
            for (int o = 0; o < NO; ++o) {
                float4 tb = s_truth[o];
                float lx = fmaxf(tb.x, px0), ly = fmaxf(tb.y, py0);
                float rx = fminf(tb.z, px1), ry = fminf(tb.w, py1);
                float w = fmaxf(rx - lx, 0.0f);
                float h = fmaxf(ry - ly, 0.0f);
                float inter = w * h;
                float iou = inter / (s_area[o] + parea - inter);
                unsigned long long key =
                    ((unsigned long long)__float_as_uint(iou) << 32) | pkey;
                best[o] = (best[o] > key) ? best[o] : key;
            }
        }
    }
#pragma unroll
    for (int o = 0; o < NO; ++o) {
        unsigned long long v = best[o];
#pragma unroll
        for (int s = 32; s > 0; s >>= 1) {
            unsigned long long u = __shfl_xor(v, s, 64);
            v = (v > u) ? v : u;
        }
        if ((threadIdx.x & 63) == 0) atomicMax(&packed[b * NO + o], v);
    }
}

__global__ __launch_bounds__(256) void fb_loss_kernel(const float4* __restrict__ loc_data,
                                                      const float2* __restrict__ conf_data,
                                                      const float4* __restrict__ priors,
                                                      const float* __restrict__ bbox,
                                                      const unsigned long long* __restrict__ packed,
                                                      double* __restrict__ acc,
                                                      unsigned int* __restrict__ npos) {
    const int b = blockIdx.x / NCH2;
    const int base = (blockIdx.x % NCH2) * (256 * IPT2);

    __shared__ float4 s_truth[NO];
    __shared__ float s_area[NO];
    __shared__ int s_label[NO];
    __shared__ int s_bpi[NO];
    if (threadIdx.x < NO) {
        const float* t = bbox + ((size_t)b * NO + threadIdx.x) * 5;
        float4 tb = make_float4(t[0], t[1], t[2], t[3]);
        s_truth[threadIdx.x] = tb;
        s_area[threadIdx.x] = (tb.z - tb.x) * (tb.w - tb.y);
        s_label[threadIdx.x] = (int)t[4];
        unsigned long long v = packed[b * NO + threadIdx.x];
        s_bpi[threadIdx.x] = (int)(0xFFFFFFFFu - (unsigned)(v & 0xFFFFFFFFull));
    }
    __syncthreads();

    float lossl = 0.0f, lossc = 0.0f;
    int np = 0;

    for (int k = 0; k < IPT2; ++k) {
        const int p = base + k * 256 + threadIdx.x;
        if (p >= NP) continue;

        float4 pr = priors[p];
        float px0 = pr.x - pr.z * 0.5f, py0 = pr.y - pr.w * 0.5f;
        float px1 = pr.x + pr.z * 0.5f, py1 = pr.y + pr.w * 0.5f;
        float parea = (px1 - px0) * (py1 - py0);

        float bestv = -1.0f;
        int bi = 0;
#pragma unroll
        for (int o = 0; o < NO; ++o) {
            float4 tb = s_truth[o];
            float lx = fmaxf(tb.x, px0), ly = fmaxf(tb.y, py0);
            float rx = fminf(tb.z, px1), ry = fminf(tb.w, py1);
            float w = fmaxf(rx - lx, 0.0f);
            float h = fmaxf(ry - ly, 0.0f);
            float inter = w * h;
            float iou = inter / (s_area[o] + parea - inter);
            if (iou > bestv) { bestv = iou; bi = o; }
        }
#pragma unroll
        for (int o = 0; o < NO; ++o) {
            if (s_bpi[o] == p) { bestv = 2.0f; bi = o; }
        }

        bool thr = !(bestv < 0.5f);
        int conf = thr ? (s_label[bi] + 1) : 0;

        if (conf > 0) {
            np++;
            float4 m = s_truth[bi];
            float gx = ((m.x + m.z) * 0.5f - pr.x) / (0.1f * pr.z);
            float gy = ((m.y + m.w) * 0.5f - pr.y) / (0.1f * pr.w);
            float gw = logf((m.z - m.x) / pr.z) / 0.2f;
            float gh = logf((m.w - m.y) / pr.w) / 0.2f;
            float4 ld = loc_data[(size_t)b * NP + p];
            float d0 = ld.x - gx, d1 = ld.y - gy, d2 = ld.z - gw, d3 = ld.w - gh;
            float a0 = fabsf(d0), a1 = fabsf(d1), a2 = fabsf(d2), a3 = fabsf(d3);
            lossl += (a0 < 1.0f) ? 0.5f * d0 * d0 : a0 - 0.5f;
            lossl += (a1 < 1.0f) ? 0.5f * d1 * d1 : a1 - 0.5f;
            lossl += (a2 < 1.0f) ? 0.5f * d2 * d2 : a2 - 0.5f;
            lossl += (a3 < 1.0f) ? 0.5f * d3 * d3 : a3 - 0.5f;
        }

        float2 cd = conf_data[(size_t)b * NP + p];
        float mx = fmaxf(cd.x, cd.y);
        float e0 = expf(cd.x - mx), e1 = expf(cd.y - mx);
        float sum = e0 + e1;
        if (conf <= 1) {
            float pc = ((conf == 0) ? e0 : e1) / sum;
            pc = fminf(fmaxf(pc, 1e-7f), 1.0f - 1e-7f);
            float om = 1.0f - pc;
            lossc += 0.25f * (-logf(pc)) * om * om;
        }
    }

#pragma unroll
    for (int s = 32; s > 0; s >>= 1) {
        lossl += __shfl_xor(lossl, s, 64);
        lossc += __shfl_xor(lossc, s, 64);
        np    += __shfl_xor(np, s, 64);
    }
    __shared__ float s_ll[4], s_lc[4];
    __shared__ int s_np[4];
    int wid = threadIdx.x >> 6;
    if ((threadIdx.x & 63) == 0) { s_ll[wid] = lossl; s_lc[wid] = lossc; s_np[wid] = np; }
    __syncthreads();
    if (threadIdx.x == 0) {
        float tl = 0.0f, tc = 0.0f;
        int tn = 0;
        for (int w = 0; w < 4; ++w) { tl += s_ll[w]; tc += s_lc[w]; tn += s_np[w]; }
        atomicAdd(&acc[0], (double)tl);
        atomicAdd(&acc[1], (double)tc);
        atomicAdd(npos, (unsigned int)tn);
    }
}

// ---------------------------------------------------------------- launcher
extern "C" void kernel_launch(void* const* d_in, const int* in_sizes, int n_in,
                              void* d_out, int out_size, void* d_ws, size_t ws_size,
                              hipStream_t stream) {
    const float4* loc_data  = (const float4*)d_in[0];
    const float2* conf_data = (const float2*)d_in[1];
    const float4* priors    = (const float4*)d_in[2];
    const float*  bbox      = (const float*)d_in[3];
    float* out = (float*)d_out;

    if (ws_size >= WS_NEEDED) {
        // fast path: u8 match-state in ws
        unsigned char* state = (unsigned char*)d_ws;
        unsigned long long* packed = (unsigned long long*)((char*)d_ws + PK_OFF);
        double* acc = (double*)((char*)d_ws + ACC_OFF);
        unsigned int* npos = (unsigned int*)((char*)d_ws + NPOS_OFF);

        init_ws_kernel<<<(NB * NO + 255) / 256, 256, 0, stream>>>(packed, acc, npos);
        match_kernel<<<NB * NCH1, 256, 0, stream>>>(priors, bbox, state, packed);
        fixup_kernel<<<NB, 64, 0, stream>>>(packed, state);
        loss_kernel<<<NB * NCH2, 256, 0, stream>>>(loc_data, conf_data, priors, bbox,
                                                   state, acc, npos);
        finalize_kernel<<<1, 64, 0, stream>>>(acc, npos, out);
    } else {
        // fallback: R1-proven path, needs only ~21 KB of ws
        unsigned long long* packed = (unsigned long long*)d_ws;
        double* acc = (double*)((char*)d_ws + (size_t)NB * NO * 8);
        unsigned int* npos = (unsigned int*)((char*)d_ws + (size_t)NB * NO * 8 + 16);

        init_ws_kernel<<<(NB * NO + 255) / 256, 256, 0, stream>>>(packed, acc, npos);
        fb_best_prior_kernel<<<NB * NCH1, 256, 0, stream>>>(priors, bbox, packed);
        fb_loss_kernel<<<NB * NCH2, 256, 0, stream>>>(loc_data, conf_data, priors, bbox,
                                                      packed, acc, npos);
        finalize_kernel<<<1, 64, 0, stream>>>(acc, npos, out);
    }
}

// Round 6
// 195.163 us; speedup vs baseline: 1.4761x; 1.4761x over previous
//
#include <hip/hip_runtime.h>

// MultiBoxLoss, contention-free 4-kernel pipeline. IoU matrix computed ONCE,
// losses fused into the match pass using PRE-fixup assignments; a tiny fixup
// kernel applies exact per-prior corrections for the <=20 overridden priors
// per image. NO same-address f64 atomics anywhere (R5 post-mortem: 3072-block
// same-address atomicAdd was a ~100us serialization floor in loss_kernel).
//
//   init    : zero per-truth packed-argmax array (2560 u64)
//   match   : per (b,p): 20 IoUs -> pre-fixup conf -> focal + smooth-L1 + npos
//             accumulated per block -> part[blockIdx] (distinct slots);
//             per-truth (iou,k) max -> packed key (iou_bits<<32|~p) atomicMax
//             (2560 addresses, ~32 ops each -> no serialization)
//   fixup   : per image: dedup best priors (last-wins), recompute the old
//             assignment for each winner prior, write the delta (new-old) of
//             focal/sl1/npos into part[1024+img]
//   finalize: one block reduces 1152 partial slots -> out[0..1]

#define NB 128
#define NP 24564
#define NO 20

#define IPT1 12
#define NCH1 8                       // 8*256*12 = 24576 >= 24564
#define NBLK1 (NB * NCH1)            // 1024 match blocks
#define NPART (NBLK1 + NB)           // 1152 partial slots

// ws layout (bytes)
#define PK_OFF 0
#define PL_OFF ((size_t)NB * NO * 8)               // 20480
#define PN_OFF (PL_OFF + (size_t)NPART * 8)        // 29696
#define WS_NEEDED (PN_OFF + (size_t)NPART * 4)     // 34304 (ws known >= 3MB from R5)

__device__ __forceinline__ float focal_term(float2 cd, int conf) {
    // EXACT reference arithmetic: softmax -> clamp -> alpha*(-log p)*(1-p)^2
    float mx = fmaxf(cd.x, cd.y);
    float e0 = expf(cd.x - mx), e1 = expf(cd.y - mx);
    float sum = e0 + e1;
    if (conf > 1) return 0.0f;                 // one_hot(conf>=2, 2) == all-zero
    float pc = ((conf == 0) ? e0 : e1) / sum;
    pc = fminf(fmaxf(pc, 1e-7f), 1.0f - 1e-7f);
    float om = 1.0f - pc;
    return 0.25f * (-logf(pc)) * om * om;
}

__device__ __forceinline__ float sl1_term(float4 m, float4 pr, float4 ld) {
    float gx = ((m.x + m.z) * 0.5f - pr.x) / (0.1f * pr.z);
    float gy = ((m.y + m.w) * 0.5f - pr.y) / (0.1f * pr.w);
    float gw = logf((m.z - m.x) / pr.z) / 0.2f;
    float gh = logf((m.w - m.y) / pr.w) / 0.2f;
    float d0 = ld.x - gx, d1 = ld.y - gy, d2 = ld.z - gw, d3 = ld.w - gh;
    float a0 = fabsf(d0), a1 = fabsf(d1), a2 = fabsf(d2), a3 = fabsf(d3);
    float r = (a0 < 1.0f) ? 0.5f * d0 * d0 : a0 - 0.5f;
    r += (a1 < 1.0f) ? 0.5f * d1 * d1 : a1 - 0.5f;
    r += (a2 < 1.0f) ? 0.5f * d2 * d2 : a2 - 0.5f;
    r += (a3 < 1.0f) ? 0.5f * d3 * d3 : a3 - 0.5f;
    return r;
}

__global__ __launch_bounds__(256) void init_ws_kernel(unsigned long long* __restrict__ packed) {
    int i = blockIdx.x * 256 + threadIdx.x;
    if (i < NB * NO) packed[i] = 0ull;
}

__global__ __launch_bounds__(256) void match_loss_kernel(
    const float4* __restrict__ loc_data,   // [B,P,4]
    const float2* __restrict__ conf_data,  // [B,P,2]
    const float4* __restrict__ priors,     // [P,4] center-form
    const float* __restrict__ bbox,        // [B,O,5]
    unsigned long long* __restrict__ packed,
    float2* __restrict__ part_loss,
    unsigned int* __restrict__ part_np)
{
    const int img  = blockIdx.x / NCH1;
    const int base = (blockIdx.x % NCH1) * (256 * IPT1);
    const int tid  = threadIdx.x;

    __shared__ float4 s_truth[NO];
    __shared__ float  s_area[NO];
    __shared__ int    s_label[NO];
    if (tid < NO) {
        const float* t = bbox + ((size_t)img * NO + tid) * 5;
        float4 tb = make_float4(t[0], t[1], t[2], t[3]);
        s_truth[tid] = tb;
        s_area[tid]  = (tb.z - tb.x) * (tb.w - tb.y);
        s_label[tid] = (int)t[4];
    }
    __syncthreads();

    // per-truth running max as (f32 iou, iteration k) -- strict > keeps
    // smallest k on ties -> smallest p within a thread (first occurrence).
    float bf[NO];
    int   bk[NO];
#pragma unroll
    for (int o = 0; o < NO; ++o) { bf[o] = -1.0f; bk[o] = 0; }

    float lossl = 0.0f, lossc = 0.0f;
    int np = 0;

    for (int k = 0; k < IPT1; ++k) {
        const int p = base + k * 256 + tid;
        if (p >= NP) break;                   // only tail chunk, monotone in k

        float4 pr = priors[p];                // center-form cx,cy,w,h
        float px0 = pr.x - pr.z * 0.5f, py0 = pr.y - pr.w * 0.5f;
        float px1 = pr.x + pr.z * 0.5f, py1 = pr.y + pr.w * 0.5f;
        float parea = (px1 - px0) * (py1 - py0);

        float bestv = -1.0f;
        int bi = 0;
#pragma unroll
        for (int o = 0; o < NO; ++o) {
            float4 tb = s_truth[o];
            float lx = fmaxf(tb.x, px0), ly = fmaxf(tb.y, py0);
            float rx = fminf(tb.z, px1), ry = fminf(tb.w, py1);
            float w = fmaxf(rx - lx, 0.0f);
            float h = fmaxf(ry - ly, 0.0f);
            float inter = w * h;
            float iou = inter / (s_area[o] + parea - inter);   // exact f32
            if (iou > bf[o]) { bf[o] = iou; bk[o] = k; }       // per-truth max
            if (iou > bestv) { bestv = iou; bi = o; }          // per-prior argmax
        }

        // PRE-fixup losses (fixup kernel corrects the <=20 overridden priors)
        const int conf = (bestv >= 0.5f) ? (s_label[bi] + 1) : 0;
        if (conf > 0) {
            np++;
            lossl += sl1_term(s_truth[bi], pr, loc_data[(size_t)img * NP + p]);
        }
        lossc += focal_term(conf_data[(size_t)img * NP + p], conf);
    }

    // per-truth keys: pack once, butterfly per wave, one atomicMax per wave
#pragma unroll
    for (int o = 0; o < NO; ++o) {
        const int p = base + bk[o] * 256 + tid;   // k=0 always executed
        unsigned long long v = ((unsigned long long)__float_as_uint(bf[o]) << 32)
                             | (unsigned long long)(0xFFFFFFFFu - (unsigned)p);
#pragma unroll
        for (int s = 32; s > 0; s >>= 1) {
            unsigned long long u = __shfl_xor(v, s, 64);
            v = (v > u) ? v : u;
        }
        if ((tid & 63) == 0) atomicMax(&packed[img * NO + o], v);
    }

    // block reduce -> private partial slot (NO same-address atomics)
#pragma unroll
    for (int s = 32; s > 0; s >>= 1) {
        lossl += __shfl_xor(lossl, s, 64);
        lossc += __shfl_xor(lossc, s, 64);
        np    += __shfl_xor(np, s, 64);
    }
    __shared__ float s_ll[4], s_lc[4];
    __shared__ int s_np4[4];
    int wid = tid >> 6;
    if ((tid & 63) == 0) { s_ll[wid] = lossl; s_lc[wid] = lossc; s_np4[wid] = np; }
    __syncthreads();
    if (tid == 0) {
        float tl = 0.0f, tc = 0.0f;
        int tn = 0;
        for (int w = 0; w < 4; ++w) { tl += s_ll[w]; tc += s_lc[w]; tn += s_np4[w]; }
        part_loss[blockIdx.x] = make_float2(tl, tc);
        part_np[blockIdx.x]   = (unsigned int)tn;
    }
}

__global__ __launch_bounds__(64) void fixup_kernel(
    const float4* __restrict__ loc_data,
    const float2* __restrict__ conf_data,
    const float4* __restrict__ priors,
    const float* __restrict__ bbox,
    const unsigned long long* __restrict__ packed,
    float2* __restrict__ part_loss,
    unsigned int* __restrict__ part_np)
{
    const int img = blockIdx.x;
    const int o   = threadIdx.x;

    __shared__ float4 s_truth[NO];
    __shared__ float  s_area[NO];
    __shared__ int    s_label[NO];
    if (o < NO) {
        const float* t = bbox + ((size_t)img * NO + o) * 5;
        float4 tb = make_float4(t[0], t[1], t[2], t[3]);
        s_truth[o] = tb;
        s_area[o]  = (tb.z - tb.x) * (tb.w - tb.y);
        s_label[o] = (int)t[4];
    }
    __syncthreads();

    int bp = -1;
    if (o < NO) {
        unsigned long long v = packed[(size_t)img * NO + o];
        bp = (int)(0xFFFFFFFFu - (unsigned)(v & 0xFFFFFFFFull));
    }
    // last-wins on duplicate best priors: only largest o with this bp applies
    bool win = (o < NO);
#pragma unroll
    for (int o2 = 0; o2 < NO; ++o2) {
        int bp2 = __shfl(bp, o2, 64);
        if (o2 > o && bp2 == bp) win = false;
    }

    float dll = 0.0f, dlc = 0.0f;
    int dnp = 0;
    if (win) {
        float4 pr = priors[bp];
        float px0 = pr.x - pr.z * 0.5f, py0 = pr.y - pr.w * 0.5f;
        float px1 = pr.x + pr.z * 0.5f, py1 = pr.y + pr.w * 0.5f;
        float parea = (px1 - px0) * (py1 - py0);

        // recompute this prior's PRE-fixup assignment (same order/ops as match)
        float bestv = -1.0f;
        int bi = 0;
#pragma unroll
        for (int o3 = 0; o3 < NO; ++o3) {
            float4 tb = s_truth[o3];
            float lx = fmaxf(tb.x, px0), ly = fmaxf(tb.y, py0);
            float rx = fminf(tb.z, px1), ry = fminf(tb.w, py1);
            float w = fmaxf(rx - lx, 0.0f);
            float h = fmaxf(ry - ly, 0.0f);
            float inter = w * h;
            float iou = inter / (s_area[o3] + parea - inter);
            if (iou > bestv) { bestv = iou; bi = o3; }
        }
        const int conf_old = (bestv >= 0.5f) ? (s_label[bi] + 1) : 0;
        const int conf_new = s_label[o] + 1;            // overlap forced to 2.0

        float2 cd = conf_data[(size_t)img * NP + bp];
        float4 ld = loc_data[(size_t)img * NP + bp];

        dlc = focal_term(cd, conf_new) - focal_term(cd, conf_old);
        float sl_new = sl1_term(s_truth[o], pr, ld);    // conf_new always > 0
        float sl_old = (conf_old > 0) ? sl1_term(s_truth[bi], pr, ld) : 0.0f;
        dll = sl_new - sl_old;
        dnp = (conf_old == 0) ? 1 : 0;
    }

    // wave reduce deltas (non-winners contribute 0) -> private slot
#pragma unroll
    for (int s = 32; s > 0; s >>= 1) {
        dll += __shfl_xor(dll, s, 64);
        dlc += __shfl_xor(dlc, s, 64);
        dnp += __shfl_xor(dnp, s, 64);
    }
    if (o == 0) {
        part_loss[NBLK1 + img] = make_float2(dll, dlc);
        part_np[NBLK1 + img]   = (unsigned int)dnp;
    }
}

__global__ __launch_bounds__(256) void finalize_kernel(
    const float2* __restrict__ part_loss,
    const unsigned int* __restrict__ part_np,
    float* __restrict__ out)
{
    double ll = 0.0, lc = 0.0;
    unsigned int np = 0;
    for (int i = threadIdx.x; i < NPART; i += 256) {
        float2 v = part_loss[i];
        ll += (double)v.x;
        lc += (double)v.y;
        np += part_np[i];
    }
#pragma unroll
    for (int s = 32; s > 0; s >>= 1) {
        ll += __shfl_xor(ll, s, 64);
        lc += __shfl_xor(lc, s, 64);
        np += __shfl_xor(np, s, 64);
    }
    __shared__ double s_ll[4], s_lc[4];
    __shared__ unsigned int s_np4[4];
    int wid = threadIdx.x >> 6;
    if ((threadIdx.x & 63) == 0) { s_ll[wid] = ll; s_lc[wid] = lc; s_np4[wid] = np; }
    __syncthreads();
    if (threadIdx.x == 0) {
        double tl = 0.0, tc = 0.0;
        unsigned int tn = 0;
        for (int w = 0; w < 4; ++w) { tl += s_ll[w]; tc += s_lc[w]; tn += s_np4[w]; }
        double npd = (tn > 0u) ? (double)tn : 1.0;
        out[0] = (float)(tl / npd);
        out[1] = (float)(tc / npd);
    }
}

extern "C" void kernel_launch(void* const* d_in, const int* in_sizes, int n_in,
                              void* d_out, int out_size, void* d_ws, size_t ws_size,
                              hipStream_t stream) {
    const float4* loc_data  = (const float4*)d_in[0];
    const float2* conf_data = (const float2*)d_in[1];
    const float4* priors    = (const float4*)d_in[2];
    const float*  bbox      = (const float*)d_in[3];
    float* out = (float*)d_out;

    unsigned long long* packed = (unsigned long long*)((char*)d_ws + PK_OFF);
    float2* part_loss = (float2*)((char*)d_ws + PL_OFF);
    unsigned int* part_np = (unsigned int*)((char*)d_ws + PN_OFF);

    init_ws_kernel<<<(NB * NO + 255) / 256, 256, 0, stream>>>(packed);
    match_loss_kernel<<<NBLK1, 256, 0, stream>>>(loc_data, conf_data, priors, bbox,
                                                 packed, part_loss, part_np);
    fixup_kernel<<<NB, 64, 0, stream>>>(loc_data, conf_data, priors, bbox,
                                        packed, part_loss, part_np);
    finalize_kernel<<<1, 256, 0, stream>>>(part_loss, part_np, out);
}

// Round 7
// 181.724 us; speedup vs baseline: 1.5852x; 1.0740x over previous
//
#include <hip/hip_runtime.h>

// MultiBoxLoss, contention-free 4-kernel pipeline. IoU matrix computed ONCE,
// losses fused into the match pass using PRE-fixup assignments; tiny fixup
// kernel applies exact per-prior corrections for <=20 overridden priors/image.
//
// R6 -> R7: hot-loop arithmetic diet. IEEE f32 div (~12-20 cy) replaced by
// v_rcp_f32 (__builtin_amdgcn_rcpf) + mul; focal's expf/logf/div replaced by
// __expf/__logf/rcp. IoU feeds only comparisons (2 argmaxes + 0.5 threshold);
// rcp's 1-2 ulp error flips a decision only on ~2ulp-ties (expected ~0.2 flips
// per launch, each worth ~1e-4 loss vs 7e-2 tolerance). fixup uses the SAME
// helpers -> match/fixup decisions bit-consistent.
//
//   init    : zero per-truth packed-argmax array (2560 u64)
//   match   : per (b,p): 20 IoUs -> pre-fixup conf -> focal + smooth-L1 + npos
//             per block -> part[blockIdx]; per-truth (iou,k) max -> packed key
//             (iou_bits<<32|~p) atomicMax (2560 addrs, ~32 ops each)
//   fixup   : per image: dedup best priors (last-wins), recompute old
//             assignment, write delta of focal/sl1/npos into part[1024+img]
//   finalize: one block reduces 1152 partial slots -> out[0..1]

#define NB 128
#define NP 24564
#define NO 20

#define IPT1 12
#define NCH1 8                       // 8*256*12 = 24576 >= 24564
#define NBLK1 (NB * NCH1)            // 1024 match blocks
#define NPART (NBLK1 + NB)           // 1152 partial slots

// ws layout (bytes)
#define PK_OFF 0
#define PL_OFF ((size_t)NB * NO * 8)               // 20480
#define PN_OFF (PL_OFF + (size_t)NPART * 8)        // 29696
#define WS_NEEDED (PN_OFF + (size_t)NPART * 4)     // 34304

__device__ __forceinline__ float fast_rcp(float x) {
    return __builtin_amdgcn_rcpf(x);               // v_rcp_f32, ~1-2 ulp
}

__device__ __forceinline__ float focal_term(float2 cd, int conf) {
    // softmax -> clamp -> alpha*(-log p)*(1-p)^2; fast exp/log/rcp (value-only,
    // no discrete decisions besides measure-zero clamp boundaries)
    float mx = fmaxf(cd.x, cd.y);
    float e0 = __expf(cd.x - mx), e1 = __expf(cd.y - mx);
    if (conf > 1) return 0.0f;                     // one_hot(conf>=2,2) == 0
    float pc = ((conf == 0) ? e0 : e1) * fast_rcp(e0 + e1);
    pc = fminf(fmaxf(pc, 1e-7f), 1.0f - 1e-7f);
    float om = 1.0f - pc;
    return 0.25f * (-__logf(pc)) * om * om;
}

__device__ __forceinline__ float sl1_term(float4 m, float4 pr, float4 ld) {
    // runs only on positives + 20 fixups/image; keep accurate div/log.
    // |d|<1 branch is continuous at the boundary (both sides = 0.5).
    float gx = ((m.x + m.z) * 0.5f - pr.x) / (0.1f * pr.z);
    float gy = ((m.y + m.w) * 0.5f - pr.y) / (0.1f * pr.w);
    float gw = logf((m.z - m.x) / pr.z) / 0.2f;
    float gh = logf((m.w - m.y) / pr.w) / 0.2f;
    float d0 = ld.x - gx, d1 = ld.y - gy, d2 = ld.z - gw, d3 = ld.w - gh;
    float a0 = fabsf(d0), a1 = fabsf(d1), a2 = fabsf(d2), a3 = fabsf(d3);
    float r = (a0 < 1.0f) ? 0.5f * d0 * d0 : a0 - 0.5f;
    r += (a1 < 1.0f) ? 0.5f * d1 * d1 : a1 - 0.5f;
    r += (a2 < 1.0f) ? 0.5f * d2 * d2 : a2 - 0.5f;
    r += (a3 < 1.0f) ? 0.5f * d3 * d3 : a3 - 0.5f;
    return r;
}

__global__ __launch_bounds__(256) void init_ws_kernel(unsigned long long* __restrict__ packed) {
    int i = blockIdx.x * 256 + threadIdx.x;
    if (i < NB * NO) packed[i] = 0ull;
}

__global__ __launch_bounds__(256) void match_loss_kernel(
    const float4* __restrict__ loc_data,   // [B,P,4]
    const float2* __restrict__ conf_data,  // [B,P,2]
    const float4* __restrict__ priors,     // [P,4] center-form
    const float* __restrict__ bbox,        // [B,O,5]
    unsigned long long* __restrict__ packed,
    float2* __restrict__ part_loss,
    unsigned int* __restrict__ part_np)
{
    const int img  = blockIdx.x / NCH1;
    const int base = (blockIdx.x % NCH1) * (256 * IPT1);
    const int tid  = threadIdx.x;

    __shared__ float4 s_truth[NO];
    __shared__ float  s_area[NO];
    __shared__ int    s_label[NO];
    if (tid < NO) {
        const float* t = bbox + ((size_t)img * NO + tid) * 5;
        float4 tb = make_float4(t[0], t[1], t[2], t[3]);
        s_truth[tid] = tb;
        s_area[tid]  = (tb.z - tb.x) * (tb.w - tb.y);
        s_label[tid] = (int)t[4];
    }
    __syncthreads();

    // per-truth running max as (f32 iou, iteration k) -- strict > keeps
    // smallest k on ties -> smallest p within a thread (first occurrence).
    float bf[NO];
    int   bk[NO];
#pragma unroll
    for (int o = 0; o < NO; ++o) { bf[o] = -1.0f; bk[o] = 0; }

    float lossl = 0.0f, lossc = 0.0f;
    int np = 0;

    for (int k = 0; k < IPT1; ++k) {
        const int p = base + k * 256 + tid;
        if (p >= NP) break;                   // only tail chunk, monotone in k

        float4 pr = priors[p];                // center-form cx,cy,w,h
        float px0 = pr.x - pr.z * 0.5f, py0 = pr.y - pr.w * 0.5f;
        float px1 = pr.x + pr.z * 0.5f, py1 = pr.y + pr.w * 0.5f;
        float parea = (px1 - px0) * (py1 - py0);

        float bestv = -1.0f;
        int bi = 0;
#pragma unroll
        for (int o = 0; o < NO; ++o) {
            float4 tb = s_truth[o];
            float lx = fmaxf(tb.x, px0), ly = fmaxf(tb.y, py0);
            float rx = fminf(tb.z, px1), ry = fminf(tb.w, py1);
            float w = fmaxf(rx - lx, 0.0f);
            float h = fmaxf(ry - ly, 0.0f);
            float inter = w * h;
            float iou = inter * fast_rcp(s_area[o] + parea - inter);
            if (iou > bf[o]) { bf[o] = iou; bk[o] = k; }       // per-truth max
            if (iou > bestv) { bestv = iou; bi = o; }          // per-prior argmax
        }

        // PRE-fixup losses (fixup kernel corrects the <=20 overridden priors)
        const int conf = (bestv >= 0.5f) ? (s_label[bi] + 1) : 0;
        if (conf > 0) {
            np++;
            lossl += sl1_term(s_truth[bi], pr, loc_data[(size_t)img * NP + p]);
        }
        lossc += focal_term(conf_data[(size_t)img * NP + p], conf);
    }

    // per-truth keys: pack once, butterfly per wave, one atomicMax per wave
#pragma unroll
    for (int o = 0; o < NO; ++o) {
        const int p = base + bk[o] * 256 + tid;   // k=0 always executed
        unsigned long long v = ((unsigned long long)__float_as_uint(bf[o]) << 32)
                             | (unsigned long long)(0xFFFFFFFFu - (unsigned)p);
#pragma unroll
        for (int s = 32; s > 0; s >>= 1) {
            unsigned long long u = __shfl_xor(v, s, 64);
            v = (v > u) ? v : u;
        }
        if ((tid & 63) == 0) atomicMax(&packed[img * NO + o], v);
    }

    // block reduce -> private partial slot (NO same-address atomics)
#pragma unroll
    for (int s = 32; s > 0; s >>= 1) {
        lossl += __shfl_xor(lossl, s, 64);
        lossc += __shfl_xor(lossc, s, 64);
        np    += __shfl_xor(np, s, 64);
    }
    __shared__ float s_ll[4], s_lc[4];
    __shared__ int s_np4[4];
    int wid = tid >> 6;
    if ((tid & 63) == 0) { s_ll[wid] = lossl; s_lc[wid] = lossc; s_np4[wid] = np; }
    __syncthreads();
    if (tid == 0) {
        float tl = 0.0f, tc = 0.0f;
        int tn = 0;
        for (int w = 0; w < 4; ++w) { tl += s_ll[w]; tc += s_lc[w]; tn += s_np4[w]; }
        part_loss[blockIdx.x] = make_float2(tl, tc);
        part_np[blockIdx.x]   = (unsigned int)tn;
    }
}

__global__ __launch_bounds__(64) void fixup_kernel(
    const float4* __restrict__ loc_data,
    const float2* __restrict__ conf_data,
    const float4* __restrict__ priors,
    const float* __restrict__ bbox,
    const unsigned long long* __restrict__ packed,
    float2* __restrict__ part_loss,
    unsigned int* __restrict__ part_np)
{
    const int img = blockIdx.x;
    const int o   = threadIdx.x;

    __shared__ float4 s_truth[NO];
    __shared__ float  s_area[NO];
    __shared__ int    s_label[NO];
    if (o < NO) {
        const float* t = bbox + ((size_t)img * NO + o) * 5;
        float4 tb = make_float4(t[0], t[1], t[2], t[3]);
        s_truth[o] = tb;
        s_area[o]  = (tb.z - tb.x) * (tb.w - tb.y);
        s_label[o] = (int)t[4];
    }
    __syncthreads();

    int bp = -1;
    if (o < NO) {
        unsigned long long v = packed[(size_t)img * NO + o];
        bp = (int)(0xFFFFFFFFu - (unsigned)(v & 0xFFFFFFFFull));
    }
    // last-wins on duplicate best priors: only largest o with this bp applies
    bool win = (o < NO);
#pragma unroll
    for (int o2 = 0; o2 < NO; ++o2) {
        int bp2 = __shfl(bp, o2, 64);
        if (o2 > o && bp2 == bp) win = false;
    }

    float dll = 0.0f, dlc = 0.0f;
    int dnp = 0;
    if (win) {
        float4 pr = priors[bp];
        float px0 = pr.x - pr.z * 0.5f, py0 = pr.y - pr.w * 0.5f;
        float px1 = pr.x + pr.z * 0.5f, py1 = pr.y + pr.w * 0.5f;
        float parea = (px1 - px0) * (py1 - py0);

        // recompute this prior's PRE-fixup assignment (same ops as match)
        float bestv = -1.0f;
        int bi = 0;
#pragma unroll
        for (int o3 = 0; o3 < NO; ++o3) {
            float4 tb = s_truth[o3];
            float lx = fmaxf(tb.x, px0), ly = fmaxf(tb.y, py0);
            float rx = fminf(tb.z, px1), ry = fminf(tb.w, py1);
            float w = fmaxf(rx - lx, 0.0f);
            float h = fmaxf(ry - ly, 0.0f);
            float inter = w * h;
            float iou = inter * fast_rcp(s_area[o3] + parea - inter);
            if (iou > bestv) { bestv = iou; bi = o3; }
        }
        const int conf_old = (bestv >= 0.5f) ? (s_label[bi] + 1) : 0;
        const int conf_new = s_label[o] + 1;            // overlap forced to 2.0

        float2 cd = conf_data[(size_t)img * NP + bp];
        float4 ld = loc_data[(size_t)img * NP + bp];

        dlc = focal_term(cd, conf_new) - focal_term(cd, conf_old);
        float sl_new = sl1_term(s_truth[o], pr, ld);    // conf_new always > 0
        float sl_old = (conf_old > 0) ? sl1_term(s_truth[bi], pr, ld) : 0.0f;
        dll = sl_new - sl_old;
        dnp = (conf_old == 0) ? 1 : 0;
    }

    // wave reduce deltas (non-winners contribute 0) -> private slot
#pragma unroll
    for (int s = 32; s > 0; s >>= 1) {
        dll += __shfl_xor(dll, s, 64);
        dlc += __shfl_xor(dlc, s, 64);
        dnp += __shfl_xor(dnp, s, 64);
    }
    if (o == 0) {
        part_loss[NBLK1 + img] = make_float2(dll, dlc);
        part_np[NBLK1 + img]   = (unsigned int)dnp;
    }
}

__global__ __launch_bounds__(256) void finalize_kernel(
    const float2* __restrict__ part_loss,
    const unsigned int* __restrict__ part_np,
    float* __restrict__ out)
{
    double ll = 0.0, lc = 0.0;
    unsigned int np = 0;
    for (int i = threadIdx.x; i < NPART; i += 256) {
        float2 v = part_loss[i];
        ll += (double)v.x;
        lc += (double)v.y;
        np += part_np[i];
    }
#pragma unroll
    for (int s = 32; s > 0; s >>= 1) {
        ll += __shfl_xor(ll, s, 64);
        lc += __shfl_xor(lc, s, 64);
        np += __shfl_xor(np, s, 64);
    }
    __shared__ double s_ll[4], s_lc[4];
    __shared__ unsigned int s_np4[4];
    int wid = threadIdx.x >> 6;
    if ((threadIdx.x & 63) == 0) { s_ll[wid] = ll; s_lc[wid] = lc; s_np4[wid] = np; }
    __syncthreads();
    if (threadIdx.x == 0) {
        double tl = 0.0, tc = 0.0;
        unsigned int tn = 0;
        for (int w = 0; w < 4; ++w) { tl += s_ll[w]; tc += s_lc[w]; tn += s_np4[w]; }
        double npd = (tn > 0u) ? (double)tn : 1.0;
        out[0] = (float)(tl / npd);
        out[1] = (float)(tc / npd);
    }
}

extern "C" void kernel_launch(void* const* d_in, const int* in_sizes, int n_in,
                              void* d_out, int out_size, void* d_ws, size_t ws_size,
                              hipStream_t stream) {
    const float4* loc_data  = (const float4*)d_in[0];
    const float2* conf_data = (const float2*)d_in[1];
    const float4* priors    = (const float4*)d_in[2];
    const float*  bbox      = (const float*)d_in[3];
    float* out = (float*)d_out;

    unsigned long long* packed = (unsigned long long*)((char*)d_ws + PK_OFF);
    float2* part_loss = (float2*)((char*)d_ws + PL_OFF);
    unsigned int* part_np = (unsigned int*)((char*)d_ws + PN_OFF);

    init_ws_kernel<<<(NB * NO + 255) / 256, 256, 0, stream>>>(packed);
    match_loss_kernel<<<NBLK1, 256, 0, stream>>>(loc_data, conf_data, priors, bbox,
                                                 packed, part_loss, part_np);
    fixup_kernel<<<NB, 64, 0, stream>>>(loc_data, conf_data, priors, bbox,
                                        packed, part_loss, part_np);
    finalize_kernel<<<1, 256, 0, stream>>>(part_loss, part_np, out);
}